// Round 1
// baseline (2165.967 us; speedup 1.0000x reference)
//
#include <hip/hip_runtime.h>
#include <hip/hip_bf16.h>
#include <stdint.h>

// ---------------- constants ----------------
#define TT 64
#define BB 32
#define NHIDC 768
#define NBK 6
#define BSZ 128
#define NTOKC 32000

using f32x4  = __attribute__((ext_vector_type(4))) float;
using short8 = __attribute__((ext_vector_type(8))) short;

// ---------------- workspace layout (bytes) ----------------
#define OFF_CNT   0u
#define OFF_S     1024u        // [2][32][6][2] f32
#define OFF_H0    4096u        // [2][32][6][128] f32
#define OFF_HC    200704u      // [4][32][6][128] f32
#define OFF_KVQ   593920u      // [8][32][6][192] f32
#define OFF_HT    1773568u     // [64][32][768] f32
#define OFF_HTB   8065024u     // [64][32][768] bf16
#define OFF_K1    11210752u    // [64][32][64] f32
#define OFF_V1    11735040u    // [64][32][512] f32
#define OFF_U     15929344u    // [64][32][6][512] f32
#define OFF_WDB   41095168u    // [32000][768] bf16   (end ~90.2MB)

__device__ __forceinline__ float sigf(float x){ return 1.f/(1.f + expf(-x)); }

__device__ __forceinline__ void gload16(const void* g, void* l){
  __builtin_amdgcn_global_load_lds(
      (const __attribute__((address_space(1))) unsigned int*)g,
      (__attribute__((address_space(3))) unsigned int*)l, 16, 0, 0);
}

// ---------------- prep: reset counters + cast Wd->bf16 ----------------
__global__ void prep_kernel(const float* __restrict__ Wd,
                            unsigned short* __restrict__ Wdb,
                            unsigned int* __restrict__ cnt)
{
  if (blockIdx.x == 0 && threadIdx.x < 128) cnt[threadIdx.x] = 0u;
  int i = blockIdx.x*blockDim.x + threadIdx.x;
  const int n = NTOKC*NHIDC;
  const int stride = gridDim.x*blockDim.x;
  for (; i < n; i += stride){
    __hip_bfloat16 h = __float2bfloat16(Wd[i]);
    Wdb[i] = *reinterpret_cast<unsigned short*>(&h);
  }
}

// ---------------- generic f32 tiled GEMM: C = A @ B ----------------
template<int TM, int TN>
__global__ __launch_bounds__(256) void gemm_f32(
    const float* __restrict__ A, int lda,
    const float* __restrict__ B, int ldb, long bstride,
    float* __restrict__ C, int ldc, long cstride,
    int N, int K)
{
  constexpr int BM = 16*TM, BN = 16*TN;
  __shared__ float As[16][BM];
  __shared__ float Bs[16][BN+4];
  const float* Bb = B + (long)blockIdx.z * bstride;
  float* Cb = C + (long)blockIdx.z * cstride;
  const int m0 = blockIdx.x*BM, n0 = blockIdx.y*BN;
  const int tid = threadIdx.x, tx = tid & 15, ty = tid >> 4;
  float acc[TM][TN];
  #pragma unroll
  for (int i=0;i<TM;++i)
    #pragma unroll
    for (int j=0;j<TN;++j) acc[i][j]=0.f;

  for (int k0=0; k0<K; k0+=16){
    if constexpr (TM == 8){
      const int r = tid>>1, kk = (tid&1)*8;
      const float4 v0 = *(const float4*)&A[(long)(m0+r)*lda + k0 + kk];
      const float4 v1 = *(const float4*)&A[(long)(m0+r)*lda + k0 + kk + 4];
      As[kk+0][r]=v0.x; As[kk+1][r]=v0.y; As[kk+2][r]=v0.z; As[kk+3][r]=v0.w;
      As[kk+4][r]=v1.x; As[kk+5][r]=v1.y; As[kk+6][r]=v1.z; As[kk+7][r]=v1.w;
    } else {
      const int r = tid>>2, kk = (tid&3)*4;
      const float4 v0 = *(const float4*)&A[(long)(m0+r)*lda + k0 + kk];
      As[kk+0][r]=v0.x; As[kk+1][r]=v0.y; As[kk+2][r]=v0.z; As[kk+3][r]=v0.w;
    }
    if constexpr (TN == 8){
      const int rb = tid>>4, cb = (tid&15)*8;
      float4 v0 = {0,0,0,0}, v1 = {0,0,0,0};
      if (n0+cb+4 <= N) v0 = *(const float4*)&Bb[(long)(k0+rb)*ldb + n0+cb];
      if (n0+cb+8 <= N) v1 = *(const float4*)&Bb[(long)(k0+rb)*ldb + n0+cb+4];
      *(float4*)&Bs[rb][cb]   = v0;
      *(float4*)&Bs[rb][cb+4] = v1;
    } else {
      const int rb = tid>>4, cb = (tid&15)*4;
      float4 v0 = {0,0,0,0};
      if (n0+cb+4 <= N) v0 = *(const float4*)&Bb[(long)(k0+rb)*ldb + n0+cb];
      *(float4*)&Bs[rb][cb] = v0;
    }
    __syncthreads();
    #pragma unroll
    for (int kk=0; kk<16; ++kk){
      float av[TM], bv[TN];
      #pragma unroll
      for (int i=0;i<TM;++i) av[i] = As[kk][ty*TM+i];
      #pragma unroll
      for (int j=0;j<TN;++j) bv[j] = Bs[kk][tx*TN+j];
      #pragma unroll
      for (int i=0;i<TM;++i)
        #pragma unroll
        for (int j=0;j<TN;++j) acc[i][j] += av[i]*bv[j];
    }
    __syncthreads();
  }
  #pragma unroll
  for (int i=0;i<TM;++i){
    const int row = m0 + ty*TM + i;
    #pragma unroll
    for (int j=0;j<TN;++j){
      const int col = n0 + tx*TN + j;
      if (col < N) Cb[(long)row*ldc + col] = acc[i][j];
    }
  }
}

// ---------------- persistent recurrent kernel ----------------
// 64 WGs x 768 threads. group g = blockIdx%8 (XCD-affine heuristic), member m = blockIdx/8.
// Group handles batches [4g, 4g+4). Member m owns h-dims Dm=[16m,16m+16) of every block.
__global__ __launch_bounds__(768, 3) void recurrent_kernel(
    const float* __restrict__ hx0, const float* __restrict__ cx0,
    const float* __restrict__ Wq_in, const float* __restrict__ Whh,
    const float* __restrict__ b_lstm,
    const float* __restrict__ Wq_c, const float* __restrict__ Wk_c,
    const float* __restrict__ Wv_c, const float* __restrict__ Wo_c,
    const float* __restrict__ K1buf, const float* __restrict__ Ubuf,
    float* __restrict__ sbuf, float* __restrict__ H0buf,
    float* __restrict__ hcbuf, float* __restrict__ kvqbuf,
    float* __restrict__ HTbuf, unsigned int* __restrict__ cnt,
    float* __restrict__ out_hx, float* __restrict__ out_cx)
{
  const int w = blockIdx.x, g = w & 7, m = w >> 3, tid = threadIdx.x;
  const int b0 = g*4;
  const int head = m >> 1, ihalf = m & 1;

  __shared__ float ld_h[4][6][128];   // current true h for group's 4 batches
  __shared__ float WqL[128][64];      // Wq_in[n==m] (m<6)
  __shared__ float gatesL[4][6][64];  // own-col gate partials, cn = gt*16+dd
  __shared__ float blL[6][4][16];
  __shared__ float cTr[4][6][16];     // c_true(t-1) own dims
  __shared__ float cNw[4][6][16];     // c_new(t)  own dims
  __shared__ float h0L[4][6][16];     // h pre-comm, own dims
  __shared__ float maskL[4][6];
  __shared__ float kvL[4][6][32];     // staged k2|v2 for own head
  __shared__ float q2L[4][3][16];
  __shared__ float attL[4][3][6];
  __shared__ float commL[4][3][16];

  unsigned int* cS = cnt + g*16 + 0;
  unsigned int* cK = cnt + g*16 + 4;
  unsigned int* cH = cnt + g*16 + 8;

  // ---- static weights -> registers ----
  const int colgrp = tid >> 3, rowgrp = tid & 7;        // Whh map
  const int wn = colgrp >> 4, colsub = colgrp & 15;
  float Wh[4][16];
  #pragma unroll
  for (int cc=0; cc<4; ++cc){
    const int cn = colsub*4 + cc;
    const int col = (cn>>4)*128 + m*16 + (cn&15);
    const float* src = Whh + wn*65536 + col;
    #pragma unroll
    for (int rr=0; rr<16; ++rr) Wh[cc][rr] = src[(rr*8 + rowgrp)*512];
  }
  const int pj = tid >> 7, pcq = (tid>>2) & 31, pdq = tid & 3;  // k2v2q2 map
  float Wc[6][4];
  #pragma unroll
  for (int cc=0; cc<6; ++cc){
    const int c192 = pcq*6 + cc;
    const int wt = c192 >> 6, wcol = c192 & 63;
    const float* src = (wt==0 ? Wk_c : (wt==1 ? Wv_c : Wq_c)) + pj*8192 + wcol;
    #pragma unroll
    for (int dr=0; dr<4; ++dr) Wc[cc][dr] = src[(m*16 + pdq*4 + dr)*64];
  }
  const int oi = tid >> 8, od = (tid>>1) & 127, okh = tid & 1;  // Wo map
  const int iglob = ihalf*3 + oi;
  float Wo[8];
  #pragma unroll
  for (int kk=0; kk<8; ++kk)
    Wo[kk] = Wo_c[iglob*8192 + (head*16 + okh*8 + kk)*128 + od];

  if (m < 6)
    for (int i = tid; i < 8192; i += 768) WqL[i>>6][i&63] = Wq_in[m*8192 + i];
  if (tid < 384){
    int n = tid>>6, gt = (tid>>4)&3, dd = tid&15;
    blL[n][gt][dd] = b_lstm[n*512 + gt*128 + m*16 + dd];
  }
  #pragma unroll
  for (int b=0; b<4; ++b) (&ld_h[0][0][0])[b*768 + tid] = hx0[(b0+b)*768 + tid];
  if (tid < 384){
    int b = tid/96, n = (tid%96)>>4, dd = tid&15;
    cTr[b][n][dd] = cx0[(b0+b)*768 + n*128 + m*16 + dd];
  }
  __syncthreads();

  for (int t = 0; t < TT; ++t){
    const int par = t & 1, parp = par ^ 1;
    if (t > 0){
      if (tid == 0){
        while (__hip_atomic_load(cH, __ATOMIC_RELAXED, __HIP_MEMORY_SCOPE_AGENT) < (unsigned)(8*t))
          __builtin_amdgcn_s_sleep(1);
        __builtin_amdgcn_fence(__ATOMIC_ACQUIRE, "agent");
      }
      __syncthreads();
      if (tid < 24){                       // mask(t-1): stable top-2 of null_att
        int b = tid/6, n = tid%6;
        float own = sbuf[parp*384 + ((b0+b)*6 + n)*2 + 1];
        int rank = 0;
        #pragma unroll
        for (int j=0; j<6; ++j){
          float v = sbuf[parp*384 + ((b0+b)*6 + j)*2 + 1];
          rank += (v > own || (v == own && j < n)) ? 1 : 0;
        }
        maskL[b][n] = (rank < 2) ? 0.f : 1.f;
      }
      __syncthreads();
      {                                    // reconstruct true h(t-1), write HT[t-1]
        const int base = tid*4;
        const int b = base/768, rem = base - b*768;
        const int n = rem >> 7, d = rem & 127;
        float4 hv;
        if (maskL[b][n] != 0.f){
          hv = *(const float4*)(H0buf + parp*24576 + ((b0+b)*6+n)*128 + d);
          #pragma unroll
          for (int h=0; h<4; ++h){
            float4 c = *(const float4*)(hcbuf + h*24576 + ((b0+b)*6+n)*128 + d);
            hv.x += c.x; hv.y += c.y; hv.z += c.z; hv.w += c.w;
          }
          *(float4*)&ld_h[b][n][d] = hv;
        } else {
          hv = *(const float4*)&ld_h[b][n][d];
        }
        if ((d>>4) == m)
          *(float4*)(HTbuf + (long)(t-1)*24576 + (b0+b)*768 + n*128 + d) = hv;
      }
      __syncthreads();
    }

    // ---- q / l1 / s / null (member m handles block n=m) ----
    if (m < 6 && tid < 256){
      const int b = tid >> 6, k = tid & 63;
      float q = 0.f;
      for (int r=0; r<128; ++r) q += ld_h[b][m][r] * WqL[r][k];
      float term = q * K1buf[(long)(t*32 + b0 + b)*64 + k];
      #pragma unroll
      for (int off=32; off; off>>=1) term += __shfl_xor(term, off);
      if (k == 0){
        float l1 = term * 0.125f;
        float mx = fmaxf(l1, 0.f);
        float e0 = expf(0.f - mx), e1 = expf(l1 - mx);
        float inv = 1.f/(e0+e1);
        sbuf[par*384 + ((b0+b)*6 + m)*2 + 0] = e1*inv;   // s = iatt1
        sbuf[par*384 + ((b0+b)*6 + m)*2 + 1] = e0*inv;   // null_att
        __hip_atomic_fetch_add(cS, 1u, __ATOMIC_RELEASE, __HIP_MEMORY_SCOPE_AGENT);
      }
    }

    // ---- gates partial: hb @ Whh (own 64 cols per block) ----
    #pragma unroll
    for (int b=0; b<4; ++b){
      float a0=0.f, a1=0.f, a2=0.f, a3=0.f;
      #pragma unroll
      for (int rr=0; rr<16; ++rr){
        const float hv = ld_h[b][wn][rr*8 + rowgrp];
        a0 += Wh[0][rr]*hv; a1 += Wh[1][rr]*hv; a2 += Wh[2][rr]*hv; a3 += Wh[3][rr]*hv;
      }
      #pragma unroll
      for (int off=1; off<8; off<<=1){
        a0 += __shfl_xor(a0, off); a1 += __shfl_xor(a1, off);
        a2 += __shfl_xor(a2, off); a3 += __shfl_xor(a3, off);
      }
      if (rowgrp == 0){
        gatesL[b][wn][colsub*4+0] = a0; gatesL[b][wn][colsub*4+1] = a1;
        gatesL[b][wn][colsub*4+2] = a2; gatesL[b][wn][colsub*4+3] = a3;
      }
    }

    if (tid == 0){
      while (__hip_atomic_load(cS, __ATOMIC_RELAXED, __HIP_MEMORY_SCOPE_AGENT) < (unsigned)(24*(t+1)))
        __builtin_amdgcn_s_sleep(1);
      __builtin_amdgcn_fence(__ATOMIC_ACQUIRE, "agent");
    }
    __syncthreads();

    // ---- pointwise LSTM (own dims) ----
    if (tid < 384){
      const int b = tid/96, n = (tid%96)>>4, dd = tid&15;
      const float sv = sbuf[par*384 + ((b0+b)*6 + n)*2 + 0];
      const long ub = ((long)(t*32 + b0 + b)*6 + n)*512 + m*16 + dd;
      const float gi = gatesL[b][n][dd]    + sv*Ubuf[ub      ] + blL[n][0][dd];
      const float gf = gatesL[b][n][16+dd] + sv*Ubuf[ub + 128] + blL[n][1][dd];
      const float gg = gatesL[b][n][32+dd] + sv*Ubuf[ub + 256] + blL[n][2][dd];
      const float go = gatesL[b][n][48+dd] + sv*Ubuf[ub + 384] + blL[n][3][dd];
      const float cpv = (t == 0) ? cTr[b][n][dd]
                      : (maskL[b][n] != 0.f ? cNw[b][n][dd] : cTr[b][n][dd]);
      cTr[b][n][dd] = cpv;
      const float cn_ = sigf(gf)*cpv + sigf(gi)*tanhf(gg);
      const float h0 = sigf(go)*tanhf(cn_);
      cNw[b][n][dd] = cn_;
      h0L[b][n][dd] = h0;
      H0buf[par*24576 + ((b0+b)*6+n)*128 + m*16 + dd] = h0;
    }
    __syncthreads();

    // ---- k2/v2/q2 partial contributions from own h dims ----
    {
      float pa[6][4];
      #pragma unroll
      for (int cc=0; cc<6; ++cc)
        #pragma unroll
        for (int b=0; b<4; ++b) pa[cc][b] = 0.f;
      #pragma unroll
      for (int b=0; b<4; ++b)
        #pragma unroll
        for (int dr=0; dr<4; ++dr){
          const float hv = h0L[b][pj][pdq*4 + dr];
          #pragma unroll
          for (int cc=0; cc<6; ++cc) pa[cc][b] += Wc[cc][dr]*hv;
        }
      #pragma unroll
      for (int cc=0; cc<6; ++cc)
        #pragma unroll
        for (int b=0; b<4; ++b){
          pa[cc][b] += __shfl_xor(pa[cc][b], 1);
          pa[cc][b] += __shfl_xor(pa[cc][b], 2);
        }
      if (pdq == 0){
        #pragma unroll
        for (int cc=0; cc<6; ++cc)
          #pragma unroll
          for (int b=0; b<4; ++b)
            kvqbuf[((m*32 + b0 + b)*6 + pj)*192 + pcq*6 + cc] = pa[cc][b];
      }
    }
    __syncthreads();
    if (tid == 0) __hip_atomic_fetch_add(cK, 1u, __ATOMIC_RELEASE, __HIP_MEMORY_SCOPE_AGENT);

    if (tid == 0){
      while (__hip_atomic_load(cK, __ATOMIC_RELAXED, __HIP_MEMORY_SCOPE_AGENT) < (unsigned)(8*(t+1)))
        __builtin_amdgcn_s_sleep(1);
      __builtin_amdgcn_fence(__ATOMIC_ACQUIRE, "agent");
    }
    __syncthreads();

    // ---- stage-reduce k2/v2 (own head) and q2 (own i-blocks) ----
    {
      const int b = tid/192, j = (tid%192)>>5, c = tid&31;
      const int c192 = (c < 16) ? (head*16 + c) : (64 + head*16 + (c-16));
      float sum = 0.f;
      #pragma unroll
      for (int mm=0; mm<8; ++mm)
        sum += kvqbuf[((mm*32 + b0 + b)*6 + j)*192 + c192];
      kvL[b][j][c] = sum;
    }
    if (tid < 192){
      const int b = tid/48, ii = (tid%48)>>4, c = tid&15;
      float sum = 0.f;
      #pragma unroll
      for (int mm=0; mm<8; ++mm)
        sum += kvqbuf[((mm*32 + b0 + b)*6 + (ihalf*3+ii))*192 + 128 + head*16 + c];
      q2L[b][ii][c] = sum;
    }
    __syncthreads();
    if (tid < 72){
      const int b = tid/18, ii = (tid%18)/6, j = tid%6;
      float lg = 0.f;
      #pragma unroll
      for (int kk=0; kk<16; ++kk) lg += q2L[b][ii][kk]*kvL[b][j][kk];
      attL[b][ii][j] = lg*0.25f;
    }
    __syncthreads();
    if (tid < 12){
      const int b = tid/3, ii = tid%3;
      float mx = attL[b][ii][0];
      #pragma unroll
      for (int j=1; j<6; ++j) mx = fmaxf(mx, attL[b][ii][j]);
      float e[6], sum = 0.f;
      #pragma unroll
      for (int j=0; j<6; ++j){ e[j] = expf(attL[b][ii][j]-mx); sum += e[j]; }
      const float inv = 1.f/sum;
      #pragma unroll
      for (int j=0; j<6; ++j) attL[b][ii][j] = e[j]*inv;
    }
    __syncthreads();
    if (tid < 192){
      const int b = tid/48, ii = (tid%48)>>4, kk = tid&15;
      float s2 = 0.f;
      #pragma unroll
      for (int j=0; j<6; ++j) s2 += attL[b][ii][j]*kvL[b][j][16+kk];
      commL[b][ii][kk] = s2;
    }
    __syncthreads();
    {
      #pragma unroll
      for (int b=0; b<4; ++b){
        float acc = 0.f;
        #pragma unroll
        for (int kk=0; kk<8; ++kk) acc += commL[b][oi][okh*8+kk]*Wo[kk];
        acc += __shfl_xor(acc, 1);
        if (okh == 0)
          hcbuf[head*24576 + ((b0+b)*6 + iglob)*128 + od] = acc;
      }
    }
    __syncthreads();
    if (tid == 0) __hip_atomic_fetch_add(cH, 1u, __ATOMIC_RELEASE, __HIP_MEMORY_SCOPE_AGENT);
  }

  // ---------------- epilogue: finalize step 63 ----------------
  if (tid == 0){
    while (__hip_atomic_load(cH, __ATOMIC_RELAXED, __HIP_MEMORY_SCOPE_AGENT) < (unsigned)(8*TT))
      __builtin_amdgcn_s_sleep(1);
    __builtin_amdgcn_fence(__ATOMIC_ACQUIRE, "agent");
  }
  __syncthreads();
  if (tid < 24){
    int b = tid/6, n = tid%6;
    float own = sbuf[1*384 + ((b0+b)*6 + n)*2 + 1];
    int rank = 0;
    #pragma unroll
    for (int j=0; j<6; ++j){
      float v = sbuf[1*384 + ((b0+b)*6 + j)*2 + 1];
      rank += (v > own || (v == own && j < n)) ? 1 : 0;
    }
    maskL[b][n] = (rank < 2) ? 0.f : 1.f;
  }
  __syncthreads();
  {
    const int base = tid*4;
    const int b = base/768, rem = base - b*768;
    const int n = rem >> 7, d = rem & 127;
    float4 hv;
    if (maskL[b][n] != 0.f){
      hv = *(const float4*)(H0buf + 1*24576 + ((b0+b)*6+n)*128 + d);
      #pragma unroll
      for (int h=0; h<4; ++h){
        float4 c = *(const float4*)(hcbuf + h*24576 + ((b0+b)*6+n)*128 + d);
        hv.x += c.x; hv.y += c.y; hv.z += c.z; hv.w += c.w;
      }
      *(float4*)&ld_h[b][n][d] = hv;
    } else {
      hv = *(const float4*)&ld_h[b][n][d];
    }
    if ((d>>4) == m){
      *(float4*)(HTbuf + (long)63*24576 + (b0+b)*768 + n*128 + d) = hv;
      *(float4*)(out_hx + (b0+b)*768 + n*128 + d) = hv;
    }
  }
  if (tid < 384){
    const int b = tid/96, n = (tid%96)>>4, dd = tid&15;
    const float cv = (maskL[b][n] != 0.f) ? cNw[b][n][dd] : cTr[b][n][dd];
    out_cx[(b0+b)*768 + n*128 + m*16 + dd] = cv;
  }
}

// ---------------- cast HT -> bf16 ----------------
__global__ void cast_ht(const float* __restrict__ in, unsigned short* __restrict__ outp, int n){
  int i = blockIdx.x*blockDim.x + threadIdx.x;
  const int stride = gridDim.x*blockDim.x;
  for (; i < n; i += stride){
    __hip_bfloat16 h = __float2bfloat16(in[i]);
    outp[i] = *reinterpret_cast<unsigned short*>(&h);
  }
}

// ---------------- decoder: out = HT @ Wd^T + bd, bf16 MFMA ----------------
__global__ __launch_bounds__(256) void decoder_kernel(
    const unsigned short* __restrict__ A,   // [2048][768] bf16
    const unsigned short* __restrict__ Bw,  // [32000][768] bf16
    const float* __restrict__ bd,
    float* __restrict__ out)
{
  __shared__ unsigned short As[4096];  // [128][32]
  __shared__ unsigned short Bs[4096];  // [128][32]
  const int m0 = blockIdx.x*128, n0 = blockIdx.y*128;
  const int tid = threadIdx.x;
  const int wv = tid >> 6, lane = tid & 63;
  const int wm = wv >> 1, wn = wv & 1;
  const int r16 = lane & 15, krow = lane >> 4;

  f32x4 acc[4][4] = {};

  for (int k0 = 0; k0 < 768; k0 += 32){
    #pragma unroll
    for (int i=0; i<2; ++i){
      const int idx = i*256 + tid;
      const int row = idx >> 2, k8 = (idx & 3)*8;
      gload16(&A [(long)(m0+row)*768 + k0 + k8], (char*)As + i*4096 + wv*1024);
      gload16(&Bw[(long)(n0+row)*768 + k0 + k8], (char*)Bs + i*4096 + wv*1024);
    }
    __syncthreads();
    short8 af[4], bf[4];
    #pragma unroll
    for (int mi=0; mi<4; ++mi)
      af[mi] = *(const short8*)&As[(wm*64 + mi*16 + r16)*32 + krow*8];
    #pragma unroll
    for (int ni=0; ni<4; ++ni)
      bf[ni] = *(const short8*)&Bs[(wn*64 + ni*16 + r16)*32 + krow*8];
    #pragma unroll
    for (int mi=0; mi<4; ++mi)
      #pragma unroll
      for (int ni=0; ni<4; ++ni)
        acc[mi][ni] = __builtin_amdgcn_mfma_f32_16x16x32_bf16(af[mi], bf[ni], acc[mi][ni], 0, 0, 0);
    __syncthreads();
  }

  #pragma unroll
  for (int ni=0; ni<4; ++ni){
    const int col = n0 + wn*64 + ni*16 + r16;
    const float bv = bd[col];
    #pragma unroll
    for (int mi=0; mi<4; ++mi){
      const int rbase = m0 + wm*64 + mi*16 + krow*4;
      #pragma unroll
      for (int j=0; j<4; ++j)
        out[(size_t)(rbase + j)*NTOKC + col] = acc[mi][ni][j] + bv;
    }
  }
}

// ---------------- launch ----------------
extern "C" void kernel_launch(void* const* d_in, const int* in_sizes, int n_in,
                              void* d_out, int out_size, void* d_ws, size_t ws_size,
                              hipStream_t stream)
{
  (void)in_sizes; (void)n_in; (void)out_size; (void)ws_size;
  const float* x      = (const float*)d_in[0];
  const float* hx0    = (const float*)d_in[1];
  const float* cx0    = (const float*)d_in[2];
  const float* Wq_in  = (const float*)d_in[3];
  const float* Wk_in  = (const float*)d_in[4];
  const float* Wv_in  = (const float*)d_in[5];
  const float* Wih    = (const float*)d_in[6];
  const float* Whh    = (const float*)d_in[7];
  const float* b_lstm = (const float*)d_in[8];
  const float* Wq_c   = (const float*)d_in[9];
  const float* Wk_c   = (const float*)d_in[10];
  const float* Wv_c   = (const float*)d_in[11];
  const float* Wo_c   = (const float*)d_in[12];
  const float* Wd     = (const float*)d_in[13];
  const float* bd     = (const float*)d_in[14];

  char* ws = (char*)d_ws;
  unsigned int*  cnt  = (unsigned int*)(ws + OFF_CNT);
  float*         sbuf = (float*)(ws + OFF_S);
  float*         H0b  = (float*)(ws + OFF_H0);
  float*         hcb  = (float*)(ws + OFF_HC);
  float*         kvqb = (float*)(ws + OFF_KVQ);
  float*         HTb  = (float*)(ws + OFF_HT);
  unsigned short* HTx = (unsigned short*)(ws + OFF_HTB);
  float*         K1b  = (float*)(ws + OFF_K1);
  float*         V1b  = (float*)(ws + OFF_V1);
  float*         Ub   = (float*)(ws + OFF_U);
  unsigned short* Wdb = (unsigned short*)(ws + OFF_WDB);

  float* out_dec = (float*)d_out;
  float* out_hx  = out_dec + (size_t)2048*NTOKC;
  float* out_cx  = out_hx + BB*NHIDC;

  // 1) reset counters + Wd -> bf16
  prep_kernel<<<2048, 256, 0, stream>>>(Wd, Wdb, cnt);
  // 2) K1 = x @ Wk_in[1]   (2048 x 64, K=768)
  gemm_f32<4,4><<<dim3(32,1,1), 256, 0, stream>>>(x, NHIDC, Wk_in + 768*64, 64, 0,
                                                  K1b, 64, 0, 64, NHIDC);
  // 3) V1 = x @ Wv_in[1]   (2048 x 512, K=768)
  gemm_f32<4,4><<<dim3(32,8,1), 256, 0, stream>>>(x, NHIDC, Wv_in + 768*512, 512, 0,
                                                  V1b, 512, 0, 512, NHIDC);
  // 4) U[:, n, :] = V1 @ Wih[n]  (2048 x 512 per n, K=512)
  gemm_f32<8,8><<<dim3(16,4,6), 256, 0, stream>>>(V1b, 512, Wih, 512, (long)512*512,
                                                  Ub, 3072, 512, 512, 512);
  // 5) recurrence (persistent, 64 WGs)
  recurrent_kernel<<<64, 768, 0, stream>>>(hx0, cx0, Wq_in, Whh, b_lstm,
                                           Wq_c, Wk_c, Wv_c, Wo_c,
                                           K1b, Ub, sbuf, H0b, hcb, kvqb, HTb,
                                           cnt, out_hx, out_cx);
  // 6) HT -> bf16
  cast_ht<<<768, 256, 0, stream>>>(HTb, HTx, TT*BB*NHIDC);
  // 7) decoder GEMM + bias
  decoder_kernel<<<dim3(16,250,1), 256, 0, stream>>>(HTx, Wdb, bd, out_dec);
}

// Round 2
// 2047.850 us; speedup vs baseline: 1.0577x; 1.0577x over previous
//
#include <hip/hip_runtime.h>
#include <hip/hip_bf16.h>
#include <stdint.h>

// ---------------- constants ----------------
#define TT 64
#define BB 32
#define NHIDC 768
#define NBK 6
#define BSZ 128
#define NTOKC 32000

using f32x4  = __attribute__((ext_vector_type(4))) float;
using short8 = __attribute__((ext_vector_type(8))) short;

// ---------------- workspace layout (bytes) ----------------
#define OFF_CNT   0u
#define OFF_S     1024u        // [2][32][6][2] f32
#define OFF_H0    4096u        // [2][32][6][128] f32
#define OFF_HC    200704u      // [4][32][6][128] f32
#define OFF_KVQ   593920u      // [8][32][6][192] f32
#define OFF_HT    1773568u     // [64][32][768] f32
#define OFF_HTB   8065024u     // [64][32][768] bf16
#define OFF_K1    11210752u    // [64][32][64] f32
#define OFF_V1    11735040u    // [64][32][512] f32
#define OFF_U     15929344u    // [64][32][6][512] f32
#define OFF_WDB   41095168u    // [32000][768] bf16
#define OFF_WHS   90247168u    // [8][12][16][64][4] f32 shuffled Whh (1.5 MB)
#define OFF_WCS   91820032u    // [8][12][6][64][4]  f32 shuffled Wc  (576 KB)
#define OFF_WOS   92409856u    // [8][12][2][64][4]  f32 shuffled Wo  (192 KB)

__device__ __forceinline__ float sigf(float x){ return 1.f/(1.f + expf(-x)); }

__device__ __forceinline__ void gload16(const void* g, void* l){
  __builtin_amdgcn_global_load_lds(
      (const __attribute__((address_space(1))) unsigned int*)g,
      (__attribute__((address_space(3))) unsigned int*)l, 16, 0, 0);
}

// ---------------- prep: reset counters + cast Wd->bf16 ----------------
__global__ void prep_kernel(const float* __restrict__ Wd,
                            unsigned short* __restrict__ Wdb,
                            unsigned int* __restrict__ cnt)
{
  if (blockIdx.x == 0 && threadIdx.x < 128) cnt[threadIdx.x] = 0u;
  int i = blockIdx.x*blockDim.x + threadIdx.x;
  const int n = NTOKC*NHIDC;
  const int stride = gridDim.x*blockDim.x;
  for (; i < n; i += stride){
    __hip_bfloat16 h = __float2bfloat16(Wd[i]);
    Wdb[i] = *reinterpret_cast<unsigned short*>(&h);
  }
}

// ---------------- shuffle weights into coalesced per-member streams ----------------
// Exact inverse of the recurrent kernel's per-thread consumption mapping.
__global__ void shuffle_w(const float* __restrict__ Whh,
                          const float* __restrict__ Wk_c, const float* __restrict__ Wv_c,
                          const float* __restrict__ Wq_c, const float* __restrict__ Wo_c,
                          float* __restrict__ WhhS, float* __restrict__ WcS,
                          float* __restrict__ WoS)
{
  int gt = blockIdx.x*blockDim.x + threadIdx.x;
  if (gt >= 8*768) return;
  const int m = gt/768, tid = gt - m*768;
  const int w = tid >> 6, l = tid & 63;
  // --- Whh slice: thread's 64 floats, k = cc*16+rr ---
  {
    const int colgrp = tid >> 3, rowgrp = tid & 7;
    const int wn = colgrp >> 4, colsub = colgrp & 15;
    for (int cc=0; cc<4; ++cc){
      const int cn = colsub*4 + cc;
      const int col = (cn>>4)*128 + m*16 + (cn&15);
      const float* src = Whh + wn*65536 + col;
      for (int rr=0; rr<16; ++rr){
        const int k = cc*16 + rr;
        WhhS[((m*12 + w)*16 + (k>>2))*256 + l*4 + (k&3)] = src[(rr*8 + rowgrp)*512];
      }
    }
  }
  // --- Wc slice: thread's 24 floats, k = dr*6+cc ---
  {
    const int pj = tid >> 7, pcq = (tid>>2) & 31, pdq = tid & 3;
    for (int cc=0; cc<6; ++cc){
      const int c192 = pcq*6 + cc;
      const int wt = c192 >> 6, wcol = c192 & 63;
      const float* src = (wt==0 ? Wk_c : (wt==1 ? Wv_c : Wq_c)) + pj*8192 + wcol;
      for (int dr=0; dr<4; ++dr){
        const int k = dr*6 + cc;
        WcS[((m*12 + w)*6 + (k>>2))*256 + l*4 + (k&3)] = src[(m*16 + pdq*4 + dr)*64];
      }
    }
  }
  // --- Wo slice: thread's 8 floats ---
  {
    const int head = m >> 1, ihalf = m & 1;
    const int oi = tid >> 8, od = (tid>>1) & 127, okh = tid & 1;
    const int iglob = ihalf*3 + oi;
    for (int kk=0; kk<8; ++kk)
      WoS[((m*12 + w)*2 + (kk>>2))*256 + l*4 + (kk&3)] =
          Wo_c[iglob*8192 + (head*16 + okh*8 + kk)*128 + od];
  }
}

// ---------------- generic f32 tiled GEMM: C = A @ B ----------------
template<int TM, int TN>
__global__ __launch_bounds__(256) void gemm_f32(
    const float* __restrict__ A, int lda,
    const float* __restrict__ B, int ldb, long bstride,
    float* __restrict__ C, int ldc, long cstride,
    int N, int K)
{
  constexpr int BM = 16*TM, BN = 16*TN;
  __shared__ float As[16][BM];
  __shared__ float Bs[16][BN+4];
  const float* Bb = B + (long)blockIdx.z * bstride;
  float* Cb = C + (long)blockIdx.z * cstride;
  const int m0 = blockIdx.x*BM, n0 = blockIdx.y*BN;
  const int tid = threadIdx.x, tx = tid & 15, ty = tid >> 4;
  float acc[TM][TN];
  #pragma unroll
  for (int i=0;i<TM;++i)
    #pragma unroll
    for (int j=0;j<TN;++j) acc[i][j]=0.f;

  for (int k0=0; k0<K; k0+=16){
    if constexpr (TM == 8){
      const int r = tid>>1, kk = (tid&1)*8;
      const float4 v0 = *(const float4*)&A[(long)(m0+r)*lda + k0 + kk];
      const float4 v1 = *(const float4*)&A[(long)(m0+r)*lda + k0 + kk + 4];
      As[kk+0][r]=v0.x; As[kk+1][r]=v0.y; As[kk+2][r]=v0.z; As[kk+3][r]=v0.w;
      As[kk+4][r]=v1.x; As[kk+5][r]=v1.y; As[kk+6][r]=v1.z; As[kk+7][r]=v1.w;
    } else {
      const int r = tid>>2, kk = (tid&3)*4;
      const float4 v0 = *(const float4*)&A[(long)(m0+r)*lda + k0 + kk];
      As[kk+0][r]=v0.x; As[kk+1][r]=v0.y; As[kk+2][r]=v0.z; As[kk+3][r]=v0.w;
    }
    if constexpr (TN == 8){
      const int rb = tid>>4, cb = (tid&15)*8;
      float4 v0 = {0,0,0,0}, v1 = {0,0,0,0};
      if (n0+cb+4 <= N) v0 = *(const float4*)&Bb[(long)(k0+rb)*ldb + n0+cb];
      if (n0+cb+8 <= N) v1 = *(const float4*)&Bb[(long)(k0+rb)*ldb + n0+cb+4];
      *(float4*)&Bs[rb][cb]   = v0;
      *(float4*)&Bs[rb][cb+4] = v1;
    } else {
      const int rb = tid>>4, cb = (tid&15)*4;
      float4 v0 = {0,0,0,0};
      if (n0+cb+4 <= N) v0 = *(const float4*)&Bb[(long)(k0+rb)*ldb + n0+cb];
      *(float4*)&Bs[rb][cb] = v0;
    }
    __syncthreads();
    #pragma unroll
    for (int kk=0; kk<16; ++kk){
      float av[TM], bv[TN];
      #pragma unroll
      for (int i=0;i<TM;++i) av[i] = As[kk][ty*TM+i];
      #pragma unroll
      for (int j=0;j<TN;++j) bv[j] = Bs[kk][tx*TN+j];
      #pragma unroll
      for (int i=0;i<TM;++i)
        #pragma unroll
        for (int j=0;j<TN;++j) acc[i][j] += av[i]*bv[j];
    }
    __syncthreads();
  }
  #pragma unroll
  for (int i=0;i<TM;++i){
    const int row = m0 + ty*TM + i;
    #pragma unroll
    for (int j=0;j<TN;++j){
      const int col = n0 + tx*TN + j;
      if (col < N) Cb[(long)row*ldc + col] = acc[i][j];
    }
  }
}

// ---------------- persistent recurrent kernel ----------------
// 64 WGs x 768 threads. group g = blockIdx%8, member m = blockIdx/8.
// Group handles batches [4g, 4g+4). Member m owns h-dims [16m,16m+16) of every block.
// Weights are streamed per step from pre-shuffled, fully-coalesced L2-hot buffers.
__global__ __launch_bounds__(768, 3) void recurrent_kernel(
    const float* __restrict__ hx0, const float* __restrict__ cx0,
    const float* __restrict__ Wq_in, const float* __restrict__ b_lstm,
    const float* __restrict__ WhhS, const float* __restrict__ WcS,
    const float* __restrict__ WoS,
    const float* __restrict__ K1buf, const float* __restrict__ Ubuf,
    float* __restrict__ sbuf, float* __restrict__ H0buf,
    float* __restrict__ hcbuf, float* __restrict__ kvqbuf,
    float* __restrict__ HTbuf, unsigned int* __restrict__ cnt,
    float* __restrict__ out_hx, float* __restrict__ out_cx)
{
  const int w = blockIdx.x, g = w & 7, m = w >> 3, tid = threadIdx.x;
  const int b0 = g*4;
  const int head = m >> 1, ihalf = m & 1;
  const int wv_ = tid >> 6, ln_ = tid & 63;

  __shared__ float ld_h[4][6][128];   // current true h for group's 4 batches
  __shared__ float WqL[64][132];      // Wq_in[n==m] transposed [k][r], +4 pad
  __shared__ float gatesL[4][6][64];
  __shared__ float blL[6][4][16];
  __shared__ float cTr[4][6][16];
  __shared__ float cNw[4][6][16];
  __shared__ float h0L[4][6][16];
  __shared__ float maskL[4][6];
  __shared__ float kvL[4][6][32];
  __shared__ float q2L[4][3][16];
  __shared__ float attL[4][3][6];
  __shared__ float commL[4][3][16];

  unsigned int* cS = cnt + g*16 + 0;
  unsigned int* cK = cnt + g*16 + 4;
  unsigned int* cH = cnt + g*16 + 8;

  // coalesced per-step weight stream bases (f32x4 granularity)
  const f32x4* whP = (const f32x4*)WhhS + (m*12 + wv_)*16*64 + ln_;
  const f32x4* wcP = (const f32x4*)WcS  + (m*12 + wv_)*6*64  + ln_;
  const f32x4* woP = (const f32x4*)WoS  + (m*12 + wv_)*2*64  + ln_;

  // Whh consumption mapping (unchanged from previous round)
  const int colgrp = tid >> 3, rowgrp = tid & 7;
  const int wn = colgrp >> 4, colsub = colgrp & 15;
  const int pj = tid >> 7, pdq = tid & 3;
  const int pcq = (tid>>2) & 31;
  const int oi = tid >> 8, od = (tid>>1) & 127, okh = tid & 1;
  const int iglob = ihalf*3 + oi;

  if (m < 6)
    for (int i = tid; i < 8192; i += 768){
      const int r = i >> 6, k = i & 63;
      WqL[k][r] = Wq_in[m*8192 + i];
    }
  if (tid < 384){
    int n = tid>>6, gt = (tid>>4)&3, dd = tid&15;
    blL[n][gt][dd] = b_lstm[n*512 + gt*128 + m*16 + dd];
  }
  #pragma unroll
  for (int b=0; b<4; ++b) (&ld_h[0][0][0])[b*768 + tid] = hx0[(b0+b)*768 + tid];
  if (tid < 384){
    int b = tid/96, n = (tid%96)>>4, dd = tid&15;
    cTr[b][n][dd] = cx0[(b0+b)*768 + n*128 + m*16 + dd];
  }
  __syncthreads();

  for (int t = 0; t < TT; ++t){
    const int par = t & 1, parp = par ^ 1;

    // ---- issue all static per-step loads early (overlap the cH wait) ----
    f32x4 wh[16], wc[6], wo2[2];
    #pragma unroll
    for (int i=0;i<16;++i) wh[i] = whP[i*64];
    #pragma unroll
    for (int i=0;i<6;++i)  wc[i] = wcP[i*64];
    #pragma unroll
    for (int i=0;i<2;++i)  wo2[i] = woP[i*64];
    float upf0=0.f, upf1=0.f, upf2=0.f, upf3=0.f, k1pf=0.f;
    if (tid < 384){
      const int b = tid/96, n = (tid%96)>>4, dd = tid&15;
      const long ub = ((long)(t*32 + b0 + b)*6 + n)*512 + m*16 + dd;
      upf0 = Ubuf[ub]; upf1 = Ubuf[ub+128]; upf2 = Ubuf[ub+256]; upf3 = Ubuf[ub+384];
    }
    if (m < 6 && tid < 256)
      k1pf = K1buf[(long)(t*32 + b0 + (tid>>6))*64 + (tid&63)];

    if (t > 0){
      if (tid == 0){
        while (__hip_atomic_load(cH, __ATOMIC_RELAXED, __HIP_MEMORY_SCOPE_AGENT) < (unsigned)(8*t))
          __builtin_amdgcn_s_sleep(1);
        __builtin_amdgcn_fence(__ATOMIC_ACQUIRE, "agent");
      }
      __syncthreads();
      if (tid < 24){                       // mask(t-1): stable top-2 of null_att
        int b = tid/6, n = tid%6;
        float own = sbuf[parp*384 + ((b0+b)*6 + n)*2 + 1];
        int rank = 0;
        #pragma unroll
        for (int j=0; j<6; ++j){
          float v = sbuf[parp*384 + ((b0+b)*6 + j)*2 + 1];
          rank += (v > own || (v == own && j < n)) ? 1 : 0;
        }
        maskL[b][n] = (rank < 2) ? 0.f : 1.f;
      }
      __syncthreads();
      {                                    // reconstruct true h(t-1), write HT[t-1]
        const int base = tid*4;
        const int b = base/768, rem = base - b*768;
        const int n = rem >> 7, d = rem & 127;
        float4 hv;
        if (maskL[b][n] != 0.f){
          hv = *(const float4*)(H0buf + parp*24576 + ((b0+b)*6+n)*128 + d);
          #pragma unroll
          for (int h=0; h<4; ++h){
            float4 c = *(const float4*)(hcbuf + h*24576 + ((b0+b)*6+n)*128 + d);
            hv.x += c.x; hv.y += c.y; hv.z += c.z; hv.w += c.w;
          }
          *(float4*)&ld_h[b][n][d] = hv;
        } else {
          hv = *(const float4*)&ld_h[b][n][d];
        }
        if ((d>>4) == m)
          *(float4*)(HTbuf + (long)(t-1)*24576 + (b0+b)*768 + n*128 + d) = hv;
      }
      __syncthreads();
    }

    // ---- q / l1 / s / null (member m handles block n=m), vectorized ----
    if (m < 6 && tid < 256){
      const int b = tid >> 6, k = tid & 63;
      f32x4 qa = {0.f,0.f,0.f,0.f};
      #pragma unroll
      for (int r4=0; r4<32; ++r4){
        const f32x4 wv4 = *(const f32x4*)&WqL[k][r4*4];
        const f32x4 hv4 = *(const f32x4*)&ld_h[b][m][r4*4];
        qa += wv4*hv4;
      }
      float term = (qa[0]+qa[1]+qa[2]+qa[3]) * k1pf;
      #pragma unroll
      for (int off=32; off; off>>=1) term += __shfl_xor(term, off);
      if (k == 0){
        float l1 = term * 0.125f;
        float mx = fmaxf(l1, 0.f);
        float e0 = expf(0.f - mx), e1 = expf(l1 - mx);
        float inv = 1.f/(e0+e1);
        sbuf[par*384 + ((b0+b)*6 + m)*2 + 0] = e1*inv;   // s = iatt1
        sbuf[par*384 + ((b0+b)*6 + m)*2 + 1] = e0*inv;   // null_att
        __hip_atomic_fetch_add(cS, 1u, __ATOMIC_RELEASE, __HIP_MEMORY_SCOPE_AGENT);
      }
    }

    // ---- gates partial: hb @ Whh (own 64 cols per block), streamed weights ----
    #pragma unroll
    for (int b=0; b<4; ++b){
      float a0=0.f, a1=0.f, a2=0.f, a3=0.f;
      #pragma unroll
      for (int rr=0; rr<16; ++rr){
        const float hv = ld_h[b][wn][rr*8 + rowgrp];
        a0 += wh[0*4 + (rr>>2)][rr&3]*hv;
        a1 += wh[1*4 + (rr>>2)][rr&3]*hv;
        a2 += wh[2*4 + (rr>>2)][rr&3]*hv;
        a3 += wh[3*4 + (rr>>2)][rr&3]*hv;
      }
      #pragma unroll
      for (int off=1; off<8; off<<=1){
        a0 += __shfl_xor(a0, off); a1 += __shfl_xor(a1, off);
        a2 += __shfl_xor(a2, off); a3 += __shfl_xor(a3, off);
      }
      if (rowgrp == 0){
        gatesL[b][wn][colsub*4+0] = a0; gatesL[b][wn][colsub*4+1] = a1;
        gatesL[b][wn][colsub*4+2] = a2; gatesL[b][wn][colsub*4+3] = a3;
      }
    }

    if (tid == 0){
      while (__hip_atomic_load(cS, __ATOMIC_RELAXED, __HIP_MEMORY_SCOPE_AGENT) < (unsigned)(24*(t+1)))
        __builtin_amdgcn_s_sleep(1);
      __builtin_amdgcn_fence(__ATOMIC_ACQUIRE, "agent");
    }
    __syncthreads();

    // ---- pointwise LSTM (own dims), uses prefetched U ----
    if (tid < 384){
      const int b = tid/96, n = (tid%96)>>4, dd = tid&15;
      const float sv = sbuf[par*384 + ((b0+b)*6 + n)*2 + 0];
      const float gi = gatesL[b][n][dd]    + sv*upf0 + blL[n][0][dd];
      const float gf = gatesL[b][n][16+dd] + sv*upf1 + blL[n][1][dd];
      const float gg = gatesL[b][n][32+dd] + sv*upf2 + blL[n][2][dd];
      const float go = gatesL[b][n][48+dd] + sv*upf3 + blL[n][3][dd];
      const float cpv = (t == 0) ? cTr[b][n][dd]
                      : (maskL[b][n] != 0.f ? cNw[b][n][dd] : cTr[b][n][dd]);
      cTr[b][n][dd] = cpv;
      const float cn_ = sigf(gf)*cpv + sigf(gi)*tanhf(gg);
      const float h0 = sigf(go)*tanhf(cn_);
      cNw[b][n][dd] = cn_;
      h0L[b][n][dd] = h0;
      H0buf[par*24576 + ((b0+b)*6+n)*128 + m*16 + dd] = h0;
    }
    __syncthreads();

    // ---- k2/v2/q2 partial contributions from own h dims (streamed Wc) ----
    {
      float pa[6][4];
      #pragma unroll
      for (int cc=0; cc<6; ++cc)
        #pragma unroll
        for (int b=0; b<4; ++b) pa[cc][b] = 0.f;
      #pragma unroll
      for (int b=0; b<4; ++b)
        #pragma unroll
        for (int dr=0; dr<4; ++dr){
          const float hv = h0L[b][pj][pdq*4 + dr];
          #pragma unroll
          for (int cc=0; cc<6; ++cc)
            pa[cc][b] += wc[(dr*6+cc)>>2][(dr*6+cc)&3]*hv;
        }
      #pragma unroll
      for (int cc=0; cc<6; ++cc)
        #pragma unroll
        for (int b=0; b<4; ++b){
          pa[cc][b] += __shfl_xor(pa[cc][b], 1);
          pa[cc][b] += __shfl_xor(pa[cc][b], 2);
        }
      if (pdq == 0){
        #pragma unroll
        for (int cc=0; cc<6; ++cc)
          #pragma unroll
          for (int b=0; b<4; ++b)
            kvqbuf[((m*32 + b0 + b)*6 + pj)*192 + pcq*6 + cc] = pa[cc][b];
      }
    }
    __syncthreads();
    if (tid == 0) __hip_atomic_fetch_add(cK, 1u, __ATOMIC_RELEASE, __HIP_MEMORY_SCOPE_AGENT);

    if (tid == 0){
      while (__hip_atomic_load(cK, __ATOMIC_RELAXED, __HIP_MEMORY_SCOPE_AGENT) < (unsigned)(8*(t+1)))
        __builtin_amdgcn_s_sleep(1);
      __builtin_amdgcn_fence(__ATOMIC_ACQUIRE, "agent");
    }
    __syncthreads();

    // ---- stage-reduce k2/v2 (own head) and q2 (own i-blocks) ----
    {
      const int b = tid/192, j = (tid%192)>>5, c = tid&31;
      const int c192 = (c < 16) ? (head*16 + c) : (64 + head*16 + (c-16));
      float sum = 0.f;
      #pragma unroll
      for (int mm=0; mm<8; ++mm)
        sum += kvqbuf[((mm*32 + b0 + b)*6 + j)*192 + c192];
      kvL[b][j][c] = sum;
    }
    if (tid < 192){
      const int b = tid/48, ii = (tid%48)>>4, c = tid&15;
      float sum = 0.f;
      #pragma unroll
      for (int mm=0; mm<8; ++mm)
        sum += kvqbuf[((mm*32 + b0 + b)*6 + (ihalf*3+ii))*192 + 128 + head*16 + c];
      q2L[b][ii][c] = sum;
    }
    __syncthreads();
    if (tid < 72){
      const int b = tid/18, ii = (tid%18)/6, j = tid%6;
      float lg = 0.f;
      #pragma unroll
      for (int kk=0; kk<16; ++kk) lg += q2L[b][ii][kk]*kvL[b][j][kk];
      attL[b][ii][j] = lg*0.25f;
    }
    __syncthreads();
    if (tid < 12){
      const int b = tid/3, ii = tid%3;
      float mx = attL[b][ii][0];
      #pragma unroll
      for (int j=1; j<6; ++j) mx = fmaxf(mx, attL[b][ii][j]);
      float e[6], sum = 0.f;
      #pragma unroll
      for (int j=0; j<6; ++j){ e[j] = expf(attL[b][ii][j]-mx); sum += e[j]; }
      const float inv = 1.f/sum;
      #pragma unroll
      for (int j=0; j<6; ++j) attL[b][ii][j] = e[j]*inv;
    }
    __syncthreads();
    if (tid < 192){
      const int b = tid/48, ii = (tid%48)>>4, kk = tid&15;
      float s2 = 0.f;
      #pragma unroll
      for (int j=0; j<6; ++j) s2 += attL[b][ii][j]*kvL[b][j][16+kk];
      commL[b][ii][kk] = s2;
    }
    __syncthreads();
    {
      #pragma unroll
      for (int b=0; b<4; ++b){
        float acc = 0.f;
        #pragma unroll
        for (int kk=0; kk<8; ++kk) acc += commL[b][oi][okh*8+kk]*wo2[kk>>2][kk&3];
        acc += __shfl_xor(acc, 1);
        if (okh == 0)
          hcbuf[head*24576 + ((b0+b)*6 + iglob)*128 + od] = acc;
      }
    }
    __syncthreads();
    if (tid == 0) __hip_atomic_fetch_add(cH, 1u, __ATOMIC_RELEASE, __HIP_MEMORY_SCOPE_AGENT);
  }

  // ---------------- epilogue: finalize step 63 ----------------
  if (tid == 0){
    while (__hip_atomic_load(cH, __ATOMIC_RELAXED, __HIP_MEMORY_SCOPE_AGENT) < (unsigned)(8*TT))
      __builtin_amdgcn_s_sleep(1);
    __builtin_amdgcn_fence(__ATOMIC_ACQUIRE, "agent");
  }
  __syncthreads();
  if (tid < 24){
    int b = tid/6, n = tid%6;
    float own = sbuf[1*384 + ((b0+b)*6 + n)*2 + 1];
    int rank = 0;
    #pragma unroll
    for (int j=0; j<6; ++j){
      float v = sbuf[1*384 + ((b0+b)*6 + j)*2 + 1];
      rank += (v > own || (v == own && j < n)) ? 1 : 0;
    }
    maskL[b][n] = (rank < 2) ? 0.f : 1.f;
  }
  __syncthreads();
  {
    const int base = tid*4;
    const int b = base/768, rem = base - b*768;
    const int n = rem >> 7, d = rem & 127;
    float4 hv;
    if (maskL[b][n] != 0.f){
      hv = *(const float4*)(H0buf + 1*24576 + ((b0+b)*6+n)*128 + d);
      #pragma unroll
      for (int h=0; h<4; ++h){
        float4 c = *(const float4*)(hcbuf + h*24576 + ((b0+b)*6+n)*128 + d);
        hv.x += c.x; hv.y += c.y; hv.z += c.z; hv.w += c.w;
      }
      *(float4*)&ld_h[b][n][d] = hv;
    } else {
      hv = *(const float4*)&ld_h[b][n][d];
    }
    if ((d>>4) == m){
      *(float4*)(HTbuf + (long)63*24576 + (b0+b)*768 + n*128 + d) = hv;
      *(float4*)(out_hx + (b0+b)*768 + n*128 + d) = hv;
    }
  }
  if (tid < 384){
    const int b = tid/96, n = (tid%96)>>4, dd = tid&15;
    const float cv = (maskL[b][n] != 0.f) ? cNw[b][n][dd] : cTr[b][n][dd];
    out_cx[(b0+b)*768 + n*128 + m*16 + dd] = cv;
  }
}

// ---------------- cast HT -> bf16 ----------------
__global__ void cast_ht(const float* __restrict__ in, unsigned short* __restrict__ outp, int n){
  int i = blockIdx.x*blockDim.x + threadIdx.x;
  const int stride = gridDim.x*blockDim.x;
  for (; i < n; i += stride){
    __hip_bfloat16 h = __float2bfloat16(in[i]);
    outp[i] = *reinterpret_cast<unsigned short*>(&h);
  }
}

// ---------------- decoder: out = HT @ Wd^T + bd, bf16 MFMA ----------------
__global__ __launch_bounds__(256) void decoder_kernel(
    const unsigned short* __restrict__ A,   // [2048][768] bf16
    const unsigned short* __restrict__ Bw,  // [32000][768] bf16
    const float* __restrict__ bd,
    float* __restrict__ out)
{
  __shared__ unsigned short As[4096];  // [128][32]
  __shared__ unsigned short Bs[4096];  // [128][32]
  const int m0 = blockIdx.x*128, n0 = blockIdx.y*128;
  const int tid = threadIdx.x;
  const int wv = tid >> 6, lane = tid & 63;
  const int wm = wv >> 1, wn = wv & 1;
  const int r16 = lane & 15, krow = lane >> 4;

  f32x4 acc[4][4] = {};

  for (int k0 = 0; k0 < 768; k0 += 32){
    #pragma unroll
    for (int i=0; i<2; ++i){
      const int idx = i*256 + tid;
      const int row = idx >> 2, k8 = (idx & 3)*8;
      gload16(&A [(long)(m0+row)*768 + k0 + k8], (char*)As + i*4096 + wv*1024);
      gload16(&Bw[(long)(n0+row)*768 + k0 + k8], (char*)Bs + i*4096 + wv*1024);
    }
    __syncthreads();
    short8 af[4], bf[4];
    #pragma unroll
    for (int mi=0; mi<4; ++mi)
      af[mi] = *(const short8*)&As[(wm*64 + mi*16 + r16)*32 + krow*8];
    #pragma unroll
    for (int ni=0; ni<4; ++ni)
      bf[ni] = *(const short8*)&Bs[(wn*64 + ni*16 + r16)*32 + krow*8];
    #pragma unroll
    for (int mi=0; mi<4; ++mi)
      #pragma unroll
      for (int ni=0; ni<4; ++ni)
        acc[mi][ni] = __builtin_amdgcn_mfma_f32_16x16x32_bf16(af[mi], bf[ni], acc[mi][ni], 0, 0, 0);
    __syncthreads();
  }

  #pragma unroll
  for (int ni=0; ni<4; ++ni){
    const int col = n0 + wn*64 + ni*16 + r16;
    const float bv = bd[col];
    #pragma unroll
    for (int mi=0; mi<4; ++mi){
      const int rbase = m0 + wm*64 + mi*16 + krow*4;
      #pragma unroll
      for (int j=0; j<4; ++j)
        out[(size_t)(rbase + j)*NTOKC + col] = acc[mi][ni][j] + bv;
    }
  }
}

// ---------------- launch ----------------
extern "C" void kernel_launch(void* const* d_in, const int* in_sizes, int n_in,
                              void* d_out, int out_size, void* d_ws, size_t ws_size,
                              hipStream_t stream)
{
  (void)in_sizes; (void)n_in; (void)out_size; (void)ws_size;
  const float* x      = (const float*)d_in[0];
  const float* hx0    = (const float*)d_in[1];
  const float* cx0    = (const float*)d_in[2];
  const float* Wq_in  = (const float*)d_in[3];
  const float* Wk_in  = (const float*)d_in[4];
  const float* Wv_in  = (const float*)d_in[5];
  const float* Wih    = (const float*)d_in[6];
  const float* Whh    = (const float*)d_in[7];
  const float* b_lstm = (const float*)d_in[8];
  const float* Wq_c   = (const float*)d_in[9];
  const float* Wk_c   = (const float*)d_in[10];
  const float* Wv_c   = (const float*)d_in[11];
  const float* Wo_c   = (const float*)d_in[12];
  const float* Wd     = (const float*)d_in[13];
  const float* bd     = (const float*)d_in[14];

  char* ws = (char*)d_ws;
  unsigned int*  cnt  = (unsigned int*)(ws + OFF_CNT);
  float*         sbuf = (float*)(ws + OFF_S);
  float*         H0b  = (float*)(ws + OFF_H0);
  float*         hcb  = (float*)(ws + OFF_HC);
  float*         kvqb = (float*)(ws + OFF_KVQ);
  float*         HTb  = (float*)(ws + OFF_HT);
  unsigned short* HTx = (unsigned short*)(ws + OFF_HTB);
  float*         K1b  = (float*)(ws + OFF_K1);
  float*         V1b  = (float*)(ws + OFF_V1);
  float*         Ub   = (float*)(ws + OFF_U);
  unsigned short* Wdb = (unsigned short*)(ws + OFF_WDB);
  float*         WhS  = (float*)(ws + OFF_WHS);
  float*         WcS  = (float*)(ws + OFF_WCS);
  float*         WoS  = (float*)(ws + OFF_WOS);

  float* out_dec = (float*)d_out;
  float* out_hx  = out_dec + (size_t)2048*NTOKC;
  float* out_cx  = out_hx + BB*NHIDC;

  // 1) reset counters + Wd -> bf16
  prep_kernel<<<2048, 256, 0, stream>>>(Wd, Wdb, cnt);
  // 1b) shuffle weights into coalesced streams
  shuffle_w<<<24, 256, 0, stream>>>(Whh, Wk_c, Wv_c, Wq_c, Wo_c, WhS, WcS, WoS);
  // 2) K1 = x @ Wk_in[1]   (2048 x 64, K=768)
  gemm_f32<4,4><<<dim3(32,1,1), 256, 0, stream>>>(x, NHIDC, Wk_in + 768*64, 64, 0,
                                                  K1b, 64, 0, 64, NHIDC);
  // 3) V1 = x @ Wv_in[1]   (2048 x 512, K=768)
  gemm_f32<4,4><<<dim3(32,8,1), 256, 0, stream>>>(x, NHIDC, Wv_in + 768*512, 512, 0,
                                                  V1b, 512, 0, 512, NHIDC);
  // 4) U[:, n, :] = V1 @ Wih[n]  (2048 x 512 per n, K=512)
  gemm_f32<8,8><<<dim3(16,4,6), 256, 0, stream>>>(V1b, 512, Wih, 512, (long)512*512,
                                                  Ub, 3072, 512, 512, 512);
  // 5) recurrence (persistent, 64 WGs)
  recurrent_kernel<<<64, 768, 0, stream>>>(hx0, cx0, Wq_in, b_lstm,
                                           WhS, WcS, WoS,
                                           K1b, Ub, sbuf, H0b, hcb, kvqb, HTb,
                                           cnt, out_hx, out_cx);
  // 6) HT -> bf16
  cast_ht<<<768, 256, 0, stream>>>(HTb, HTx, TT*BB*NHIDC);
  // 7) decoder GEMM + bias
  decoder_kernel<<<dim3(16,250,1), 256, 0, stream>>>(HTx, Wdb, bd, out_dec);
}

// Round 3
// 2024.796 us; speedup vs baseline: 1.0697x; 1.0114x over previous
//
#include <hip/hip_runtime.h>
#include <hip/hip_bf16.h>
#include <stdint.h>

// ---------------- constants ----------------
#define TT 64
#define BB 32
#define NHIDC 768
#define NBK 6
#define BSZ 128
#define NTOKC 32000

using f32x4  = __attribute__((ext_vector_type(4))) float;
using short8 = __attribute__((ext_vector_type(8))) short;

// ---------------- workspace layout (bytes) ----------------
#define OFF_CNT   0u
#define OFF_S     1024u        // [2][32][6][2] f32
#define OFF_H0    4096u        // [2][32][6][128] f32
#define OFF_KVQ   593920u      // [8][32][6][192] f32
#define OFF_HT    1773568u     // [64][32][768] f32
#define OFF_HTB   8065024u     // [64][32][768] bf16
#define OFF_K1    11210752u    // [64][32][64] f32
#define OFF_V1    11735040u    // [64][32][512] f32
#define OFF_U     15929344u    // [64][32][6][512] f32
#define OFF_WDB   41095168u    // [32000][768] bf16
#define OFF_WHS   90247168u    // [8][12][16][64][4] f32 shuffled Whh (1.5 MB)
#define OFF_WCS   91820032u    // [8][12][6][64][4]  f32 shuffled Wc  (576 KB)
#define OFF_WOS   92409856u    // [8][12][2][64][4]  f32 shuffled Wo  (192 KB)

__device__ __forceinline__ float sigf(float x){ return 1.f/(1.f + expf(-x)); }

__device__ __forceinline__ void gload16(const void* g, void* l){
  __builtin_amdgcn_global_load_lds(
      (const __attribute__((address_space(1))) unsigned int*)g,
      (__attribute__((address_space(3))) unsigned int*)l, 16, 0, 0);
}

// ---------------- prep: reset counters + cast Wd->bf16 ----------------
__global__ void prep_kernel(const float* __restrict__ Wd,
                            unsigned short* __restrict__ Wdb,
                            unsigned int* __restrict__ cnt)
{
  if (blockIdx.x == 0 && threadIdx.x < 128) cnt[threadIdx.x] = 0u;
  int i = blockIdx.x*blockDim.x + threadIdx.x;
  const int n = NTOKC*NHIDC;
  const int stride = gridDim.x*blockDim.x;
  for (; i < n; i += stride){
    __hip_bfloat16 h = __float2bfloat16(Wd[i]);
    Wdb[i] = *reinterpret_cast<unsigned short*>(&h);
  }
}

// ---------------- shuffle weights into coalesced per-member streams ----------------
__global__ void shuffle_w(const float* __restrict__ Whh,
                          const float* __restrict__ Wk_c, const float* __restrict__ Wv_c,
                          const float* __restrict__ Wq_c, const float* __restrict__ Wo_c,
                          float* __restrict__ WhhS, float* __restrict__ WcS,
                          float* __restrict__ WoS)
{
  int gt = blockIdx.x*blockDim.x + threadIdx.x;
  if (gt >= 8*768) return;
  const int m = gt/768, tid = gt - m*768;
  const int w = tid >> 6, l = tid & 63;
  // --- Whh slice: thread's 64 floats, k = cc*16+rr ---
  {
    const int colgrp = tid >> 3, rowgrp = tid & 7;
    const int wn = colgrp >> 4, colsub = colgrp & 15;
    for (int cc=0; cc<4; ++cc){
      const int cn = colsub*4 + cc;
      const int col = (cn>>4)*128 + m*16 + (cn&15);
      const float* src = Whh + wn*65536 + col;
      for (int rr=0; rr<16; ++rr){
        const int k = cc*16 + rr;
        WhhS[((m*12 + w)*16 + (k>>2))*256 + l*4 + (k&3)] = src[(rr*8 + rowgrp)*512];
      }
    }
  }
  // --- Wc slice: thread's 24 floats, k = dr*6+cc ---
  {
    const int pj = tid >> 7, pcq = (tid>>2) & 31, pdq = tid & 3;
    for (int cc=0; cc<6; ++cc){
      const int c192 = pcq*6 + cc;
      const int wt = c192 >> 6, wcol = c192 & 63;
      const float* src = (wt==0 ? Wk_c : (wt==1 ? Wv_c : Wq_c)) + pj*8192 + wcol;
      for (int dr=0; dr<4; ++dr){
        const int k = dr*6 + cc;
        WcS[((m*12 + w)*6 + (k>>2))*256 + l*4 + (k&3)] = src[(m*16 + pdq*4 + dr)*64];
      }
    }
  }
  // --- Wo slice: thread's 8 floats ---
  {
    const int head = m >> 1, ihalf = m & 1;
    const int oi = tid >> 8, od = (tid>>1) & 127, okh = tid & 1;
    const int iglob = ihalf*3 + oi;
    for (int kk=0; kk<8; ++kk)
      WoS[((m*12 + w)*2 + (kk>>2))*256 + l*4 + (kk&3)] =
          Wo_c[iglob*8192 + (head*16 + okh*8 + kk)*128 + od];
  }
}

// ---------------- generic f32 tiled GEMM: C = A @ B ----------------
template<int TM, int TN>
__global__ __launch_bounds__(256) void gemm_f32(
    const float* __restrict__ A, int lda,
    const float* __restrict__ B, int ldb, long bstride,
    float* __restrict__ C, int ldc, long cstride,
    int N, int K)
{
  constexpr int BM = 16*TM, BN = 16*TN;
  __shared__ float As[16][BM];
  __shared__ float Bs[16][BN+4];
  const float* Bb = B + (long)blockIdx.z * bstride;
  float* Cb = C + (long)blockIdx.z * cstride;
  const int m0 = blockIdx.x*BM, n0 = blockIdx.y*BN;
  const int tid = threadIdx.x, tx = tid & 15, ty = tid >> 4;
  float acc[TM][TN];
  #pragma unroll
  for (int i=0;i<TM;++i)
    #pragma unroll
    for (int j=0;j<TN;++j) acc[i][j]=0.f;

  for (int k0=0; k0<K; k0+=16){
    if constexpr (TM == 8){
      const int r = tid>>1, kk = (tid&1)*8;
      const float4 v0 = *(const float4*)&A[(long)(m0+r)*lda + k0 + kk];
      const float4 v1 = *(const float4*)&A[(long)(m0+r)*lda + k0 + kk + 4];
      As[kk+0][r]=v0.x; As[kk+1][r]=v0.y; As[kk+2][r]=v0.z; As[kk+3][r]=v0.w;
      As[kk+4][r]=v1.x; As[kk+5][r]=v1.y; As[kk+6][r]=v1.z; As[kk+7][r]=v1.w;
    } else {
      const int r = tid>>2, kk = (tid&3)*4;
      const float4 v0 = *(const float4*)&A[(long)(m0+r)*lda + k0 + kk];
      As[kk+0][r]=v0.x; As[kk+1][r]=v0.y; As[kk+2][r]=v0.z; As[kk+3][r]=v0.w;
    }
    if constexpr (TN == 8){
      const int rb = tid>>4, cb = (tid&15)*8;
      float4 v0 = {0,0,0,0}, v1 = {0,0,0,0};
      if (n0+cb+4 <= N) v0 = *(const float4*)&Bb[(long)(k0+rb)*ldb + n0+cb];
      if (n0+cb+8 <= N) v1 = *(const float4*)&Bb[(long)(k0+rb)*ldb + n0+cb+4];
      *(float4*)&Bs[rb][cb]   = v0;
      *(float4*)&Bs[rb][cb+4] = v1;
    } else {
      const int rb = tid>>4, cb = (tid&15)*4;
      float4 v0 = {0,0,0,0};
      if (n0+cb+4 <= N) v0 = *(const float4*)&Bb[(long)(k0+rb)*ldb + n0+cb];
      *(float4*)&Bs[rb][cb] = v0;
    }
    __syncthreads();
    #pragma unroll
    for (int kk=0; kk<16; ++kk){
      float av[TM], bv[TN];
      #pragma unroll
      for (int i=0;i<TM;++i) av[i] = As[kk][ty*TM+i];
      #pragma unroll
      for (int j=0;j<TN;++j) bv[j] = Bs[kk][tx*TN+j];
      #pragma unroll
      for (int i=0;i<TM;++i)
        #pragma unroll
        for (int j=0;j<TN;++j) acc[i][j] += av[i]*bv[j];
    }
    __syncthreads();
  }
  #pragma unroll
  for (int i=0;i<TM;++i){
    const int row = m0 + ty*TM + i;
    #pragma unroll
    for (int j=0;j<TN;++j){
      const int col = n0 + tx*TN + j;
      if (col < N) Cb[(long)row*ldc + col] = acc[i][j];
    }
  }
}

// ---------------- persistent recurrent kernel ----------------
// 64 WGs x 768 threads. group g = blockIdx%8, member m = blockIdx/8.
// Group handles batches [4g, 4g+4). Member m owns h-dims [16m,16m+16) of every block.
// Weights live in PINNED registers (loaded once). h-exchange merged: Wo-reduce
// atomicAdds comm into H0buf so the step-top reconstruct is a single float4 read.
__global__ __launch_bounds__(768, 3) void recurrent_kernel(
    const float* __restrict__ hx0, const float* __restrict__ cx0,
    const float* __restrict__ Wq_in, const float* __restrict__ b_lstm,
    const float* __restrict__ WhhS, const float* __restrict__ WcS,
    const float* __restrict__ WoS,
    const float* __restrict__ K1buf, const float* __restrict__ Ubuf,
    float* __restrict__ sbuf, float* __restrict__ H0buf,
    float* __restrict__ kvqbuf,
    float* __restrict__ HTbuf, unsigned int* __restrict__ cnt,
    float* __restrict__ out_hx, float* __restrict__ out_cx)
{
  const int w = blockIdx.x, g = w & 7, m = w >> 3, tid = threadIdx.x;
  const int b0 = g*4;
  const int head = m >> 1, ihalf = m & 1;
  const int wv_ = tid >> 6, ln_ = tid & 63;

  __shared__ float ld_h[4][6][128];   // current true h for group's 4 batches
  __shared__ float WqL[64][132];      // Wq_in[n==m] transposed [k][r], +4 pad
  __shared__ float gatesL[4][6][64];
  __shared__ float blL[6][4][16];
  __shared__ float cTr[4][6][16];
  __shared__ float cNw[4][6][16];
  __shared__ float h0L[4][6][16];
  __shared__ float maskL[4][6];
  __shared__ float kvL[4][6][32];
  __shared__ float q2L[4][3][16];
  __shared__ float commL[4][3][16];

  unsigned int* cS = cnt + g*16 + 0;
  unsigned int* cK = cnt + g*16 + 4;
  unsigned int* cH = cnt + g*16 + 8;

  // coalesced weight stream bases (f32x4 granularity)
  const f32x4* whP = (const f32x4*)WhhS + (m*12 + wv_)*16*64 + ln_;
  const f32x4* wcP = (const f32x4*)WcS  + (m*12 + wv_)*6*64  + ln_;
  const f32x4* woP = (const f32x4*)WoS  + (m*12 + wv_)*2*64  + ln_;

  // consumption mappings
  const int colgrp = tid >> 3, rowgrp = tid & 7;
  const int wn = colgrp >> 4, colsub = colgrp & 15;
  const int pj = tid >> 7, pdq = tid & 3;
  const int pcq = (tid>>2) & 31;
  const int oi = tid >> 8, od = (tid>>1) & 127, okh = tid & 1;
  const int iglob = ihalf*3 + oi;

  // ---- load weights ONCE into registers and pin them ----
  f32x4 wh[16], wc[6], wo2[2];
  #pragma unroll
  for (int i=0;i<16;++i) wh[i] = whP[i*64];
  #pragma unroll
  for (int i=0;i<6;++i)  wc[i] = wcP[i*64];
  #pragma unroll
  for (int i=0;i<2;++i)  wo2[i] = woP[i*64];
  // pin wh & wc (88 VGPRs): makes values opaque -> loads cannot be sunk into
  // the t-loop. wo2 left unpinned (2 loads/step worst case, tail-phase only).
  #pragma unroll
  for (int i=0;i<16;++i) asm volatile("" : "+v"(wh[i]));
  #pragma unroll
  for (int i=0;i<6;++i)  asm volatile("" : "+v"(wc[i]));

  if (m < 6)
    for (int i = tid; i < 8192; i += 768){
      const int r = i >> 6, k = i & 63;
      WqL[k][r] = Wq_in[m*8192 + i];
    }
  if (tid < 384){
    int n = tid>>6, gt = (tid>>4)&3, dd = tid&15;
    blL[n][gt][dd] = b_lstm[n*512 + gt*128 + m*16 + dd];
  }
  #pragma unroll
  for (int b=0; b<4; ++b) (&ld_h[0][0][0])[b*768 + tid] = hx0[(b0+b)*768 + tid];
  if (tid < 384){
    int b = tid/96, n = (tid%96)>>4, dd = tid&15;
    cTr[b][n][dd] = cx0[(b0+b)*768 + n*128 + m*16 + dd];
  }
  __syncthreads();

  for (int t = 0; t < TT; ++t){
    const int par = t & 1, parp = par ^ 1;

    // ---- per-step data prefetch (U, K1) ----
    float upf0=0.f, upf1=0.f, upf2=0.f, upf3=0.f, k1pf=0.f;
    if (tid < 384){
      const int b = tid/96, n = (tid%96)>>4, dd = tid&15;
      const long ub = ((long)(t*32 + b0 + b)*6 + n)*512 + m*16 + dd;
      upf0 = Ubuf[ub]; upf1 = Ubuf[ub+128]; upf2 = Ubuf[ub+256]; upf3 = Ubuf[ub+384];
    }
    if (m < 6 && tid < 256)
      k1pf = K1buf[(long)(t*32 + b0 + (tid>>6))*64 + (tid&63)];

    if (t > 0){
      if (tid == 0){
        while (__hip_atomic_load(cH, __ATOMIC_RELAXED, __HIP_MEMORY_SCOPE_AGENT) < (unsigned)(8*t))
          __builtin_amdgcn_s_sleep(1);
        __builtin_amdgcn_fence(__ATOMIC_ACQUIRE, "agent");
      }
      __syncthreads();
      if (tid < 24){                       // mask(t-1): stable top-2 of null_att
        int b = tid/6, n = tid%6;
        float own = sbuf[parp*384 + ((b0+b)*6 + n)*2 + 1];
        int rank = 0;
        #pragma unroll
        for (int j=0; j<6; ++j){
          float v = sbuf[parp*384 + ((b0+b)*6 + j)*2 + 1];
          rank += (v > own || (v == own && j < n)) ? 1 : 0;
        }
        maskL[b][n] = (rank < 2) ? 0.f : 1.f;
      }
      __syncthreads();
      {                                    // select true h(t-1) (H0 = h0+comm), write HT[t-1]
        const int base = tid*4;
        const int b = base/768, rem = base - b*768;
        const int n = rem >> 7, d = rem & 127;
        float4 hv;
        if (maskL[b][n] != 0.f){
          hv = *(const float4*)(H0buf + parp*24576 + ((b0+b)*6+n)*128 + d);
          *(float4*)&ld_h[b][n][d] = hv;
        } else {
          hv = *(const float4*)&ld_h[b][n][d];
        }
        if ((d>>4) == m)
          *(float4*)(HTbuf + (long)(t-1)*24576 + (b0+b)*768 + n*128 + d) = hv;
      }
      __syncthreads();
    }

    // ---- q / l1 / s / null (member m handles block n=m), vectorized ----
    if (m < 6 && tid < 256){
      const int b = tid >> 6, k = tid & 63;
      f32x4 qa = {0.f,0.f,0.f,0.f};
      #pragma unroll
      for (int r4=0; r4<32; ++r4){
        const f32x4 wv4 = *(const f32x4*)&WqL[k][r4*4];
        const f32x4 hv4 = *(const f32x4*)&ld_h[b][m][r4*4];
        qa += wv4*hv4;
      }
      float term = (qa[0]+qa[1]+qa[2]+qa[3]) * k1pf;
      #pragma unroll
      for (int off=32; off; off>>=1) term += __shfl_xor(term, off);
      if (k == 0){
        float l1 = term * 0.125f;
        float mx = fmaxf(l1, 0.f);
        float e0 = expf(0.f - mx), e1 = expf(l1 - mx);
        float inv = 1.f/(e0+e1);
        sbuf[par*384 + ((b0+b)*6 + m)*2 + 0] = e1*inv;   // s = iatt1
        sbuf[par*384 + ((b0+b)*6 + m)*2 + 1] = e0*inv;   // null_att
        __hip_atomic_fetch_add(cS, 1u, __ATOMIC_RELEASE, __HIP_MEMORY_SCOPE_AGENT);
      }
    }

    // ---- gates partial: hb @ Whh (own 64 cols per block), register weights ----
    #pragma unroll
    for (int b=0; b<4; ++b){
      float a0=0.f, a1=0.f, a2=0.f, a3=0.f;
      #pragma unroll
      for (int rr=0; rr<16; ++rr){
        const float hv = ld_h[b][wn][rr*8 + rowgrp];
        a0 += wh[0*4 + (rr>>2)][rr&3]*hv;
        a1 += wh[1*4 + (rr>>2)][rr&3]*hv;
        a2 += wh[2*4 + (rr>>2)][rr&3]*hv;
        a3 += wh[3*4 + (rr>>2)][rr&3]*hv;
      }
      #pragma unroll
      for (int off=1; off<8; off<<=1){
        a0 += __shfl_xor(a0, off); a1 += __shfl_xor(a1, off);
        a2 += __shfl_xor(a2, off); a3 += __shfl_xor(a3, off);
      }
      if (rowgrp == 0){
        gatesL[b][wn][colsub*4+0] = a0; gatesL[b][wn][colsub*4+1] = a1;
        gatesL[b][wn][colsub*4+2] = a2; gatesL[b][wn][colsub*4+3] = a3;
      }
    }

    if (tid == 0){
      while (__hip_atomic_load(cS, __ATOMIC_RELAXED, __HIP_MEMORY_SCOPE_AGENT) < (unsigned)(24*(t+1)))
        __builtin_amdgcn_s_sleep(1);
      __builtin_amdgcn_fence(__ATOMIC_ACQUIRE, "agent");
    }
    __syncthreads();

    // ---- pointwise LSTM (own dims), uses prefetched U ----
    if (tid < 384){
      const int b = tid/96, n = (tid%96)>>4, dd = tid&15;
      const float sv = sbuf[par*384 + ((b0+b)*6 + n)*2 + 0];
      const float gi = gatesL[b][n][dd]    + sv*upf0 + blL[n][0][dd];
      const float gf = gatesL[b][n][16+dd] + sv*upf1 + blL[n][1][dd];
      const float gg = gatesL[b][n][32+dd] + sv*upf2 + blL[n][2][dd];
      const float go = gatesL[b][n][48+dd] + sv*upf3 + blL[n][3][dd];
      const float cpv = (t == 0) ? cTr[b][n][dd]
                      : (maskL[b][n] != 0.f ? cNw[b][n][dd] : cTr[b][n][dd]);
      cTr[b][n][dd] = cpv;
      const float cn_ = sigf(gf)*cpv + sigf(gi)*tanhf(gg);
      const float h0 = sigf(go)*tanhf(cn_);
      cNw[b][n][dd] = cn_;
      h0L[b][n][dd] = h0;
      H0buf[par*24576 + ((b0+b)*6+n)*128 + m*16 + dd] = h0;
    }
    __syncthreads();

    // ---- k2/v2/q2 partial contributions from own h dims (register Wc) ----
    {
      float pa[6][4];
      #pragma unroll
      for (int cc=0; cc<6; ++cc)
        #pragma unroll
        for (int b=0; b<4; ++b) pa[cc][b] = 0.f;
      #pragma unroll
      for (int b=0; b<4; ++b)
        #pragma unroll
        for (int dr=0; dr<4; ++dr){
          const float hv = h0L[b][pj][pdq*4 + dr];
          #pragma unroll
          for (int cc=0; cc<6; ++cc)
            pa[cc][b] += wc[(dr*6+cc)>>2][(dr*6+cc)&3]*hv;
        }
      #pragma unroll
      for (int cc=0; cc<6; ++cc)
        #pragma unroll
        for (int b=0; b<4; ++b){
          pa[cc][b] += __shfl_xor(pa[cc][b], 1);
          pa[cc][b] += __shfl_xor(pa[cc][b], 2);
        }
      if (pdq == 0){
        #pragma unroll
        for (int cc=0; cc<6; ++cc)
          #pragma unroll
          for (int b=0; b<4; ++b)
            kvqbuf[((m*32 + b0 + b)*6 + pj)*192 + pcq*6 + cc] = pa[cc][b];
      }
    }
    __syncthreads();
    if (tid == 0) __hip_atomic_fetch_add(cK, 1u, __ATOMIC_RELEASE, __HIP_MEMORY_SCOPE_AGENT);

    if (tid == 0){
      while (__hip_atomic_load(cK, __ATOMIC_RELAXED, __HIP_MEMORY_SCOPE_AGENT) < (unsigned)(8*(t+1)))
        __builtin_amdgcn_s_sleep(1);
      __builtin_amdgcn_fence(__ATOMIC_ACQUIRE, "agent");
    }
    __syncthreads();

    // ---- stage-reduce k2/v2 (own head) and q2 (own i-blocks) ----
    {
      const int b = tid/192, j = (tid%192)>>5, c = tid&31;
      const int c192 = (c < 16) ? (head*16 + c) : (64 + head*16 + (c-16));
      float sum = 0.f;
      #pragma unroll
      for (int mm=0; mm<8; ++mm)
        sum += kvqbuf[((mm*32 + b0 + b)*6 + j)*192 + c192];
      kvL[b][j][c] = sum;
    }
    if (tid < 192){
      const int b = tid/48, ii = (tid%48)>>4, c = tid&15;
      float sum = 0.f;
      #pragma unroll
      for (int mm=0; mm<8; ++mm)
        sum += kvqbuf[((mm*32 + b0 + b)*6 + (ihalf*3+ii))*192 + 128 + head*16 + c];
      q2L[b][ii][c] = sum;
    }
    __syncthreads();
    // ---- full attention per (b,i) in one lane: logits+softmax+comm ----
    if (tid < 12){
      const int b = tid/3, ii = tid%3;
      float q2r[16];
      #pragma unroll
      for (int kk=0; kk<16; ++kk) q2r[kk] = q2L[b][ii][kk];
      float lg[6], mx = -1e30f;
      #pragma unroll
      for (int j=0; j<6; ++j){
        float s = 0.f;
        #pragma unroll
        for (int kk=0; kk<16; ++kk) s += q2r[kk]*kvL[b][j][kk];
        lg[j] = s*0.25f;
        mx = fmaxf(mx, lg[j]);
      }
      float sum = 0.f;
      #pragma unroll
      for (int j=0; j<6; ++j){ lg[j] = expf(lg[j]-mx); sum += lg[j]; }
      const float inv = 1.f/sum;
      #pragma unroll
      for (int kk=0; kk<16; ++kk){
        float s2 = 0.f;
        #pragma unroll
        for (int j=0; j<6; ++j) s2 += lg[j]*inv*kvL[b][j][16+kk];
        commL[b][ii][kk] = s2;
      }
    }
    __syncthreads();
    // ---- Wo-reduce: atomicAdd comm contribution onto H0buf (h_new = h0+comm) ----
    {
      #pragma unroll
      for (int b=0; b<4; ++b){
        float acc = 0.f;
        #pragma unroll
        for (int kk=0; kk<8; ++kk) acc += commL[b][oi][okh*8+kk]*wo2[kk>>2][kk&3];
        acc += __shfl_xor(acc, 1);
        if (okh == 0)
          __hip_atomic_fetch_add(H0buf + par*24576 + ((b0+b)*6 + iglob)*128 + od,
                                 acc, __ATOMIC_RELAXED, __HIP_MEMORY_SCOPE_AGENT);
      }
    }
    __syncthreads();
    if (tid == 0) __hip_atomic_fetch_add(cH, 1u, __ATOMIC_RELEASE, __HIP_MEMORY_SCOPE_AGENT);
  }

  // ---------------- epilogue: finalize step 63 ----------------
  if (tid == 0){
    while (__hip_atomic_load(cH, __ATOMIC_RELAXED, __HIP_MEMORY_SCOPE_AGENT) < (unsigned)(8*TT))
      __builtin_amdgcn_s_sleep(1);
    __builtin_amdgcn_fence(__ATOMIC_ACQUIRE, "agent");
  }
  __syncthreads();
  if (tid < 24){
    int b = tid/6, n = tid%6;
    float own = sbuf[1*384 + ((b0+b)*6 + n)*2 + 1];
    int rank = 0;
    #pragma unroll
    for (int j=0; j<6; ++j){
      float v = sbuf[1*384 + ((b0+b)*6 + j)*2 + 1];
      rank += (v > own || (v == own && j < n)) ? 1 : 0;
    }
    maskL[b][n] = (rank < 2) ? 0.f : 1.f;
  }
  __syncthreads();
  {
    const int base = tid*4;
    const int b = base/768, rem = base - b*768;
    const int n = rem >> 7, d = rem & 127;
    float4 hv;
    if (maskL[b][n] != 0.f){
      hv = *(const float4*)(H0buf + 1*24576 + ((b0+b)*6+n)*128 + d);
      *(float4*)&ld_h[b][n][d] = hv;
    } else {
      hv = *(const float4*)&ld_h[b][n][d];
    }
    if ((d>>4) == m){
      *(float4*)(HTbuf + (long)63*24576 + (b0+b)*768 + n*128 + d) = hv;
      *(float4*)(out_hx + (b0+b)*768 + n*128 + d) = hv;
    }
  }
  if (tid < 384){
    const int b = tid/96, n = (tid%96)>>4, dd = tid&15;
    const float cv = (maskL[b][n] != 0.f) ? cNw[b][n][dd] : cTr[b][n][dd];
    out_cx[(b0+b)*768 + n*128 + m*16 + dd] = cv;
  }
}

// ---------------- cast HT -> bf16 ----------------
__global__ void cast_ht(const float* __restrict__ in, unsigned short* __restrict__ outp, int n){
  int i = blockIdx.x*blockDim.x + threadIdx.x;
  const int stride = gridDim.x*blockDim.x;
  for (; i < n; i += stride){
    __hip_bfloat16 h = __float2bfloat16(in[i]);
    outp[i] = *reinterpret_cast<unsigned short*>(&h);
  }
}

// ---------------- decoder: out = HT @ Wd^T + bd, bf16 MFMA ----------------
__global__ __launch_bounds__(256) void decoder_kernel(
    const unsigned short* __restrict__ A,   // [2048][768] bf16
    const unsigned short* __restrict__ Bw,  // [32000][768] bf16
    const float* __restrict__ bd,
    float* __restrict__ out)
{
  __shared__ unsigned short As[4096];  // [128][32]
  __shared__ unsigned short Bs[4096];  // [128][32]
  const int m0 = blockIdx.x*128, n0 = blockIdx.y*128;
  const int tid = threadIdx.x;
  const int wv = tid >> 6, lane = tid & 63;
  const int wm = wv >> 1, wn = wv & 1;
  const int r16 = lane & 15, krow = lane >> 4;

  f32x4 acc[4][4] = {};

  for (int k0 = 0; k0 < 768; k0 += 32){
    #pragma unroll
    for (int i=0; i<2; ++i){
      const int idx = i*256 + tid;
      const int row = idx >> 2, k8 = (idx & 3)*8;
      gload16(&A [(long)(m0+row)*768 + k0 + k8], (char*)As + i*4096 + wv*1024);
      gload16(&Bw[(long)(n0+row)*768 + k0 + k8], (char*)Bs + i*4096 + wv*1024);
    }
    __syncthreads();
    short8 af[4], bf[4];
    #pragma unroll
    for (int mi=0; mi<4; ++mi)
      af[mi] = *(const short8*)&As[(wm*64 + mi*16 + r16)*32 + krow*8];
    #pragma unroll
    for (int ni=0; ni<4; ++ni)
      bf[ni] = *(const short8*)&Bs[(wn*64 + ni*16 + r16)*32 + krow*8];
    #pragma unroll
    for (int mi=0; mi<4; ++mi)
      #pragma unroll
      for (int ni=0; ni<4; ++ni)
        acc[mi][ni] = __builtin_amdgcn_mfma_f32_16x16x32_bf16(af[mi], bf[ni], acc[mi][ni], 0, 0, 0);
    __syncthreads();
  }

  #pragma unroll
  for (int ni=0; ni<4; ++ni){
    const int col = n0 + wn*64 + ni*16 + r16;
    const float bv = bd[col];
    #pragma unroll
    for (int mi=0; mi<4; ++mi){
      const int rbase = m0 + wm*64 + mi*16 + krow*4;
      #pragma unroll
      for (int j=0; j<4; ++j)
        out[(size_t)(rbase + j)*NTOKC + col] = acc[mi][ni][j] + bv;
    }
  }
}

// ---------------- launch ----------------
extern "C" void kernel_launch(void* const* d_in, const int* in_sizes, int n_in,
                              void* d_out, int out_size, void* d_ws, size_t ws_size,
                              hipStream_t stream)
{
  (void)in_sizes; (void)n_in; (void)out_size; (void)ws_size;
  const float* x      = (const float*)d_in[0];
  const float* hx0    = (const float*)d_in[1];
  const float* cx0    = (const float*)d_in[2];
  const float* Wq_in  = (const float*)d_in[3];
  const float* Wk_in  = (const float*)d_in[4];
  const float* Wv_in  = (const float*)d_in[5];
  const float* Wih    = (const float*)d_in[6];
  const float* Whh    = (const float*)d_in[7];
  const float* b_lstm = (const float*)d_in[8];
  const float* Wq_c   = (const float*)d_in[9];
  const float* Wk_c   = (const float*)d_in[10];
  const float* Wv_c   = (const float*)d_in[11];
  const float* Wo_c   = (const float*)d_in[12];
  const float* Wd     = (const float*)d_in[13];
  const float* bd     = (const float*)d_in[14];

  char* ws = (char*)d_ws;
  unsigned int*  cnt  = (unsigned int*)(ws + OFF_CNT);
  float*         sbuf = (float*)(ws + OFF_S);
  float*         H0b  = (float*)(ws + OFF_H0);
  float*         kvqb = (float*)(ws + OFF_KVQ);
  float*         HTb  = (float*)(ws + OFF_HT);
  unsigned short* HTx = (unsigned short*)(ws + OFF_HTB);
  float*         K1b  = (float*)(ws + OFF_K1);
  float*         V1b  = (float*)(ws + OFF_V1);
  float*         Ub   = (float*)(ws + OFF_U);
  unsigned short* Wdb = (unsigned short*)(ws + OFF_WDB);
  float*         WhS  = (float*)(ws + OFF_WHS);
  float*         WcS  = (float*)(ws + OFF_WCS);
  float*         WoS  = (float*)(ws + OFF_WOS);

  float* out_dec = (float*)d_out;
  float* out_hx  = out_dec + (size_t)2048*NTOKC;
  float* out_cx  = out_hx + BB*NHIDC;

  // 1) reset counters + Wd -> bf16
  prep_kernel<<<2048, 256, 0, stream>>>(Wd, Wdb, cnt);
  // 1b) shuffle weights into coalesced streams
  shuffle_w<<<24, 256, 0, stream>>>(Whh, Wk_c, Wv_c, Wq_c, Wo_c, WhS, WcS, WoS);
  // 2) K1 = x @ Wk_in[1]   (2048 x 64, K=768)
  gemm_f32<4,4><<<dim3(32,1,1), 256, 0, stream>>>(x, NHIDC, Wk_in + 768*64, 64, 0,
                                                  K1b, 64, 0, 64, NHIDC);
  // 3) V1 = x @ Wv_in[1]   (2048 x 512, K=768)
  gemm_f32<4,4><<<dim3(32,8,1), 256, 0, stream>>>(x, NHIDC, Wv_in + 768*512, 512, 0,
                                                  V1b, 512, 0, 512, NHIDC);
  // 4) U[:, n, :] = V1 @ Wih[n]  (2048 x 512 per n, K=512)
  gemm_f32<8,8><<<dim3(16,4,6), 256, 0, stream>>>(V1b, 512, Wih, 512, (long)512*512,
                                                  Ub, 3072, 512, 512, 512);
  // 5) recurrence (persistent, 64 WGs)
  recurrent_kernel<<<64, 768, 0, stream>>>(hx0, cx0, Wq_in, b_lstm,
                                           WhS, WcS, WoS,
                                           K1b, Ub, sbuf, H0b, kvqb, HTb,
                                           cnt, out_hx, out_cx);
  // 6) HT -> bf16
  cast_ht<<<768, 256, 0, stream>>>(HTb, HTx, TT*BB*NHIDC);
  // 7) decoder GEMM + bias
  decoder_kernel<<<dim3(16,250,1), 256, 0, stream>>>(HTx, Wdb, bd, out_dec);
}